// Round 8
// baseline (621.634 us; speedup 1.0000x reference)
//
#include <hip/hip_runtime.h>
#include <hip/hip_bf16.h>

#define DIM 128
#define LVL 8

typedef unsigned int u32;
typedef unsigned short u16;

using bf16x8 = __attribute__((ext_vector_type(8))) short;
using f32x4  = __attribute__((ext_vector_type(4))) float;

__device__ __forceinline__ float bf2f(u16 u) { union { u32 i; float f; } v; v.i = ((u32)u) << 16; return v.f; }
__device__ __forceinline__ u16 f2bf(float f) { __hip_bfloat16 b = __float2bfloat16(f); return *reinterpret_cast<u16*>(&b); }
__device__ __forceinline__ u32 pk2(float lo, float hi) { return (u32)f2bf(lo) | ((u32)f2bf(hi) << 16); }
__device__ __forceinline__ float sigf(float x) { return 1.f / (1.f + __expf(-x)); }
__device__ __forceinline__ float tanhfast(float x) { return 1.f - 2.f / (__expf(2.f * x) + 1.f); }

// ---- level offsets + root fan-in ----
__global__ void k_levels(const int* __restrict__ depth, int n, int* __restrict__ ofs, int* __restrict__ deg) {
  int d = threadIdx.x;
  if (d <= LVL) {
    int lo = 0, hi = n;
    while (lo < hi) { int mid = (lo + hi) >> 1; if (depth[mid] < d) lo = mid + 1; else hi = mid; }
    ofs[d] = lo;
  }
  __syncthreads();
  if (d == 0) deg[0] = ofs[2] - ofs[1];
}

// ---- fan-in counts for non-root parents ----
__global__ void k_mark(const int* __restrict__ parent, const int* __restrict__ depth, int n,
                       int* __restrict__ deg) {
  int j = blockIdx.x * blockDim.x + threadIdx.x;
  if (j >= n) return;
  if (depth[j] < 2) return;
  int p = parent[j];
  if (p >= 0 && p < n) atomicAdd(&deg[p], 1);
}

// ---- zero hsum/fcsum rows that receive atomic accumulation (deg>=2) ----
__global__ void k_zero(const int* __restrict__ deg, int n, float* __restrict__ hsum, float* __restrict__ fcsum) {
  int row = blockIdx.x * 4 + (threadIdx.x >> 6);
  if (row >= n) return;
  if (deg[row] < 2) return;
  int l = threadIdx.x & 63;
  float2 z; z.x = 0.f; z.y = 0.f;
  *(float2*)(hsum + (size_t)row * DIM + l * 2) = z;
  *(float2*)(fcsum + (size_t)row * DIM + l * 2) = z;
}

// ---- bf16 transposed weights. WcT natural-k (for k_big). WhTp/WfhTp k-PERMUTED:
// row c, position j holds W[perm(j)][c], perm(j) = (j&7)*16 + (j>>3) — matches the
// [m][nt] register order of MFMA C fragments, so hsum/fcsum stay in j-order end to end.
__global__ void k_prep(const float* __restrict__ Wioux, const float* __restrict__ Wiouh,
                       const float* __restrict__ Wfx, const float* __restrict__ Wfh,
                       u16* __restrict__ WcT, u16* __restrict__ WhTp, u16* __restrict__ WfhTp) {
  int i = blockIdx.x * 256 + threadIdx.x;
  if (i >= 1024 * 128) return;
  int c = i >> 7, k = i & 127;
  if (c < 512) {
    float v = (c < 384) ? Wioux[(size_t)k * 384 + c] : Wfx[(size_t)k * 128 + (c - 384)];
    WcT[(size_t)c * 128 + k] = f2bf(v);
  } else {
    int kp = (k & 7) * 16 + (k >> 3);           // perm(j), j=k
    if (c < 896) {
      int cc = c - 512;
      WhTp[(size_t)cc * 128 + k] = f2bf(Wiouh[(size_t)kp * 384 + cc]);
    } else {
      int cc = c - 896;
      WfhTp[(size_t)cc * 128 + k] = f2bf(Wfh[(size_t)kp * 128 + cc]);
    }
  }
}

// ---- xi = x @ [Wioux|Wfx] (MFMA bf16); xi layout [v][gate][m][nt] u16 (unchanged) ----
__global__ __launch_bounds__(256) void k_big(const float* __restrict__ x, const u16* __restrict__ WcT,
                                             const int* __restrict__ deg, u16* __restrict__ xi, int n) {
  __shared__ __align__(16) char smem[16384 + 32768];
  char* xsb = smem;
  char* wtb = smem + 16384;
  __shared__ int flg[64];
  __shared__ int s_any;
  int tid = threadIdx.x;
  int wave = tid >> 6, lane = tid & 63, m = lane & 15, kg = lane >> 4;
  int row0 = blockIdx.x * 64;
  if (tid < 64) flg[tid] = (row0 + tid < n) ? (deg[row0 + tid] > 0) : 0;
  __syncthreads();
  if (tid == 0) { int a = 0; for (int r = 0; r < 64; ++r) a |= flg[r]; s_any = a; }
  __syncthreads();
  if (!s_any) return;
  for (int i = tid; i < 64 * 16; i += 256) {
    int r = i >> 4, c8 = (i & 15) * 8;
    int gr = row0 + r;
    uint4 o = make_uint4(0u, 0u, 0u, 0u);
    if (gr < n) {
      float4 a = *(const float4*)(x + (size_t)gr * DIM + c8);
      float4 b = *(const float4*)(x + (size_t)gr * DIM + c8 + 4);
      o = make_uint4(pk2(a.x, a.y), pk2(a.z, a.w), pk2(b.x, b.y), pk2(b.z, b.w));
    }
    *(uint4*)(xsb + r * 256 + ((c8 * 2) ^ ((r & 7) << 4))) = o;
  }
  int arow = wave * 16 + m;
  for (int ci = 0; ci < 4; ++ci) {
    if (ci) __syncthreads();
    for (int i = tid; i < 128 * 16; i += 256) {
      int cl = i >> 4, k8 = (i & 15) * 8;
      uint4 v = *(const uint4*)(WcT + (size_t)(ci * 128 + cl) * 128 + k8);
      *(uint4*)(wtb + cl * 256 + ((k8 * 2) ^ ((cl & 7) << 4))) = v;
    }
    __syncthreads();
    f32x4 acc[8];
    #pragma unroll
    for (int nt = 0; nt < 8; ++nt) acc[nt] = (f32x4){0.f, 0.f, 0.f, 0.f};
    #pragma unroll
    for (int kk = 0; kk < 4; ++kk) {
      int kbyte = kk * 64 + kg * 16;
      bf16x8 a = *(const bf16x8*)(xsb + arow * 256 + (kbyte ^ ((arow & 7) << 4)));
      #pragma unroll
      for (int nt = 0; nt < 8; ++nt) {
        int col = nt * 16 + m;
        bf16x8 b = *(const bf16x8*)(wtb + col * 256 + (kbyte ^ ((col & 7) << 4)));
        acc[nt] = __builtin_amdgcn_mfma_f32_16x16x32_bf16(a, b, acc[nt], 0, 0, 0);
      }
    }
    #pragma unroll
    for (int r = 0; r < 4; ++r) {
      int rl = wave * 16 + kg * 4 + r;
      int gr = row0 + rl;
      if (gr < n && flg[rl]) {
        uint4 o = make_uint4(pk2(acc[0][r], acc[1][r]), pk2(acc[2][r], acc[3][r]),
                             pk2(acc[4][r], acc[5][r]), pk2(acc[6][r], acc[7][r]));
        *(uint4*)(xi + (((size_t)gr * 4 + ci) * 16 + m) * 8) = o;
      }
    }
  }
}

// ---- wave-autonomous per-level kernel: one wave = one 16-row tile, NO block barriers ----
__global__ __launch_bounds__(256) void k_wave(const float* __restrict__ x,
    const u16* __restrict__ WhTp, const u16* __restrict__ WfhTp, const u16* __restrict__ xi,
    const int* __restrict__ deg, const int* __restrict__ parent, const int* __restrict__ ofs,
    float* __restrict__ hout, float* hsum, float* fcsum,
    float* __restrict__ ph, float* __restrict__ pfc, int n, int d) {
  __shared__ __align__(16) char smem[16384];     // 4 waves x 16 rows x 256B bf16 (swizzled)
  int tid = threadIdx.x;
  int wid = tid >> 6, lane = tid & 63, m = lane & 15, kg = lane >> 4;
  char* hsb = smem + wid * 4096;
  int v0 = ofs[d], v1 = ofs[d + 1];
  int gw = (int)blockIdx.x * 4 + wid;            // global tile index
  int row0 = v0 + gw * 16;
  if (row0 >= v1) return;                        // whole wave exits; no barriers anywhere

  // ---- meta (per lane: 4 rows rl = kg*4+r) ----
  int pr[4], dgp[4];
  bool act[4], leaf[4];
  bool anyNL = false;
  #pragma unroll
  for (int r = 0; r < 4; ++r) {
    int grow = row0 + kg * 4 + r;
    act[r] = grow < v1;
    int gc = min(grow, n - 1);
    leaf[r] = deg[gc] == 0;
    pr[r] = parent[gc];
    dgp[r] = deg[pr[r]];
    anyNL |= (act[r] && !leaf[r]);
  }
  bool anyp = __ballot(anyNL) != 0ull;

  // ---- stage hsum rows (j-order -> bf16, swizzled); zeros for leaf/inactive ----
  if (anyp) {
    #pragma unroll
    for (int it = 0; it < 4; ++it) {
      int idx = lane + it * 64;
      int r = idx >> 4, ch = idx & 15;
      int grow = row0 + r;
      uint4 o = make_uint4(0u, 0u, 0u, 0u);
      if (grow < v1 && deg[grow] > 0) {
        const float* hp = hsum + (size_t)grow * DIM + ch * 8;
        float4 a = *(const float4*)hp; float4 b = *(const float4*)(hp + 4);
        o = make_uint4(pk2(a.x, a.y), pk2(a.z, a.w), pk2(b.x, b.y), pk2(b.z, b.w));
      }
      *(uint4*)(hsb + r * 256 + ((ch * 16) ^ ((r & 7) << 4))) = o;
    }
  }

  // ---- iou MFMA in 3 phases (i, u, o) to cap registers; B direct from global (L1/L2) ----
  float P[8][4];   // sig(i), then sig(i)*tanh(u)
  float O[8][4];   // sig(o)
  const int cxs[3] = {0, 2, 1};
  #pragma unroll
  for (int phx = 0; phx < 3; ++phx) {
    int cx = cxs[phx];
    f32x4 acc[8];
    #pragma unroll
    for (int nt = 0; nt < 8; ++nt) acc[nt] = (f32x4){0.f, 0.f, 0.f, 0.f};
    if (anyp) {
      #pragma unroll
      for (int kk = 0; kk < 4; ++kk) {
        int kel = kk * 32 + kg * 8;
        bf16x8 a = *(const bf16x8*)(hsb + m * 256 + ((kel * 2) ^ ((m & 7) << 4)));
        #pragma unroll
        for (int nt = 0; nt < 8; ++nt) {
          bf16x8 b = *(const bf16x8*)(WhTp + (size_t)(cx * 128 + nt * 16 + m) * 128 + kel);
          acc[nt] = __builtin_amdgcn_mfma_f32_16x16x32_bf16(a, b, acc[nt], 0, 0, 0);
        }
      }
    }
    #pragma unroll
    for (int r = 0; r < 4; ++r) {
      int gc = min(row0 + kg * 4 + r, n - 1);
      uint4 q = *(const uint4*)(xi + (((size_t)gc * 4 + cx) * 16 + m) * 8);
      #pragma unroll
      for (int nt = 0; nt < 8; ++nt) {
        float t = bf2f(((const u16*)&q)[nt]) + acc[nt][r];
        if (phx == 0)      P[nt][r] = sigf(t);
        else if (phx == 1) P[nt][r] *= tanhfast(t);
        else               O[nt][r] = sigf(t);
      }
    }
  }

  // ---- epilogue: h,c; hout; h-bf16 into hsb (j-order, 16B/row vector write) ----
  float hv[8][4], cv[8][4];
  #pragma unroll
  for (int r = 0; r < 4; ++r) {
    int rl = kg * 4 + r;
    int grow = row0 + rl;
    int gc = min(grow, n - 1);
    float4 fa = *(const float4*)(fcsum + (size_t)gc * DIM + m * 8);
    float4 fb = *(const float4*)(fcsum + (size_t)gc * DIM + m * 8 + 4);
    #pragma unroll
    for (int nt = 0; nt < 8; ++nt) {
      float xv = x[(size_t)gc * DIM + nt * 16 + m];
      float fcv = (nt < 4) ? ((const float*)&fa)[nt] : ((const float*)&fb)[nt - 4];
      float c_ = leaf[r] ? tanhfast(xv) : fcv + P[nt][r];
      float h_ = leaf[r] ? xv : O[nt][r] * tanhfast(c_);
      if (!act[r]) { c_ = 0.f; h_ = 0.f; }
      cv[nt][r] = c_; hv[nt][r] = h_;
      if (act[r]) hout[(size_t)grow * DIM + nt * 16 + m] = h_;
    }
    uint4 o = make_uint4(pk2(hv[0][r], hv[1][r]), pk2(hv[2][r], hv[3][r]),
                         pk2(hv[4][r], hv[5][r]), pk2(hv[6][r], hv[7][r]));
    *(uint4*)(hsb + rl * 256 + ((m * 16) ^ ((rl & 7) << 4))) = o;
  }

  // ---- f-pre MFMA: A = this wave's h from hsb (lgkmcnt orders the RAW in-wave) ----
  f32x4 fp[8];
  #pragma unroll
  for (int nt = 0; nt < 8; ++nt) fp[nt] = (f32x4){0.f, 0.f, 0.f, 0.f};
  #pragma unroll
  for (int kk = 0; kk < 4; ++kk) {
    int kel = kk * 32 + kg * 8;
    bf16x8 a = *(const bf16x8*)(hsb + m * 256 + ((kel * 2) ^ ((m & 7) << 4)));
    #pragma unroll
    for (int nt = 0; nt < 8; ++nt) {
      bf16x8 b = *(const bf16x8*)(WfhTp + (size_t)(nt * 16 + m) * 128 + kel);
      fp[nt] = __builtin_amdgcn_mfma_f32_16x16x32_bf16(a, b, fp[nt], 0, 0, 0);
    }
  }

  // ---- scatter ----
  if (d == 1) {
    // all parents = root: in-wave reduce, write per-wave partials (no atomics)
    uint4 qf = *(const uint4*)(xi + ((size_t)(3 * 16 + m)) * 8);   // xf[0]
    float th[8], tf[8];
    #pragma unroll
    for (int nt = 0; nt < 8; ++nt) {
      float sh = 0.f, sf = 0.f;
      #pragma unroll
      for (int r = 0; r < 4; ++r) {
        sh += hv[nt][r];
        sf += act[r] ? sigf(bf2f(((const u16*)&qf)[nt]) + fp[nt][r]) * cv[nt][r] : 0.f;
      }
      th[nt] = sh; tf[nt] = sf;
    }
    #pragma unroll
    for (int nt = 0; nt < 8; ++nt) {
      th[nt] += __shfl_xor(th[nt], 16, 64); th[nt] += __shfl_xor(th[nt], 32, 64);
      tf[nt] += __shfl_xor(tf[nt], 16, 64); tf[nt] += __shfl_xor(tf[nt], 32, 64);
    }
    if (kg == 0) {
      float4 h0 = make_float4(th[0], th[1], th[2], th[3]);
      float4 h1 = make_float4(th[4], th[5], th[6], th[7]);
      float4 f0 = make_float4(tf[0], tf[1], tf[2], tf[3]);
      float4 f1 = make_float4(tf[4], tf[5], tf[6], tf[7]);
      *(float4*)(ph  + (size_t)gw * DIM + m * 8)     = h0;
      *(float4*)(ph  + (size_t)gw * DIM + m * 8 + 4) = h1;
      *(float4*)(pfc + (size_t)gw * DIM + m * 8)     = f0;
      *(float4*)(pfc + (size_t)gw * DIM + m * 8 + 4) = f1;
    }
  } else {
    #pragma unroll
    for (int r = 0; r < 4; ++r) {
      if (!act[r]) continue;
      int p = pr[r];
      uint4 qf = *(const uint4*)(xi + (((size_t)p * 4 + 3) * 16 + m) * 8);
      float fc[8];
      #pragma unroll
      for (int nt = 0; nt < 8; ++nt)
        fc[nt] = sigf(bf2f(((const u16*)&qf)[nt]) + fp[nt][r]) * cv[nt][r];
      if (dgp[r] == 1) {
        float4 h0 = make_float4(hv[0][r], hv[1][r], hv[2][r], hv[3][r]);
        float4 h1 = make_float4(hv[4][r], hv[5][r], hv[6][r], hv[7][r]);
        float4 f0 = make_float4(fc[0], fc[1], fc[2], fc[3]);
        float4 f1 = make_float4(fc[4], fc[5], fc[6], fc[7]);
        *(float4*)(hsum  + (size_t)p * DIM + m * 8)     = h0;
        *(float4*)(hsum  + (size_t)p * DIM + m * 8 + 4) = h1;
        *(float4*)(fcsum + (size_t)p * DIM + m * 8)     = f0;
        *(float4*)(fcsum + (size_t)p * DIM + m * 8 + 4) = f1;
      } else {
        #pragma unroll
        for (int nt = 0; nt < 8; ++nt) {
          atomicAdd(hsum  + (size_t)p * DIM + m * 8 + nt, hv[nt][r]);
          atomicAdd(fcsum + (size_t)p * DIM + m * 8 + nt, fc[nt]);
        }
      }
    }
  }
}

// ---- root: reduce level-1 partials, dense 384-dot, gates ----
__global__ void k_root(const float* __restrict__ x, const u16* __restrict__ WhTp,
                       const u16* __restrict__ xi, const int* __restrict__ deg,
                       const int* __restrict__ ofs, const float* __restrict__ ph,
                       const float* __restrict__ pfc, float* __restrict__ hout) {
  __shared__ float hs[128], fcs[128], pre[384], tmp[256], tmp2[256];
  int tid = threadIdx.x;
  if (deg[0] == 0) { if (tid < 128) hout[tid] = x[tid]; return; }
  int n1 = ofs[2] - ofs[1];
  int nw = (n1 + 15) >> 4;
  int j = tid & 127, half = tid >> 7;
  float sh = 0.f, sf = 0.f;
  for (int w = half; w < nw; w += 2) {
    sh += ph[(size_t)w * DIM + j];
    sf += pfc[(size_t)w * DIM + j];
  }
  tmp[tid] = sh; tmp2[tid] = sf;
  __syncthreads();
  if (tid < 128) { hs[tid] = tmp[tid] + tmp[tid + 128]; fcs[tid] = tmp2[tid] + tmp2[tid + 128]; }
  __syncthreads();
  for (int c = tid; c < 384; c += 256) {
    float a = 0.f;
    const u16* wr = WhTp + (size_t)c * 128;
    for (int k = 0; k < 128; ++k) a += hs[k] * bf2f(wr[k]);
    pre[c] = a;
  }
  __syncthreads();
  if (tid < 128) {
    int m = tid & 15, nt = tid >> 4;
    float iv = bf2f(xi[((size_t)(0 * 16 + m)) * 8 + nt]) + pre[tid];
    float ov = bf2f(xi[((size_t)(1 * 16 + m)) * 8 + nt]) + pre[128 + tid];
    float uv = bf2f(xi[((size_t)(2 * 16 + m)) * 8 + nt]) + pre[256 + tid];
    float fcv = fcs[m * 8 + nt];
    float ci_ = fcv + sigf(iv) * tanhfast(uv);
    hout[tid] = sigf(ov) * tanhfast(ci_);
  }
}

extern "C" void kernel_launch(void* const* d_in, const int* in_sizes, int n_in,
                              void* d_out, int out_size, void* d_ws, size_t ws_size,
                              hipStream_t stream) {
  const float* x    = (const float*)d_in[0];
  const int* parent = (const int*)d_in[1];
  const int* depth  = (const int*)d_in[2];
  const float* Wioux = (const float*)d_in[3];
  const float* Wiouh = (const float*)d_in[4];
  const float* Wfx   = (const float*)d_in[5];
  const float* Wfh   = (const float*)d_in[6];
  int n = in_sizes[0] / DIM;
  float* h = (float*)d_out;

  int maxw = (n + 15) / 16 + 8;
  u16*   WcT   = (u16*)d_ws;                             // 512*128
  u16*   WhTp  = WcT + 512 * 128;                        // 384*128 (k-permuted)
  u16*   WfhTp = WhTp + 384 * 128;                       // 128*128 (k-permuted)
  u16*   xi    = WfhTp + 128 * 128;                      // n*512 ([v][gate][m][nt])
  float* hsum  = (float*)(xi + (size_t)n * 512);         // n*128 (j-order)
  float* fcsum = hsum + (size_t)n * DIM;                 // n*128 (j-order)
  float* ph    = fcsum + (size_t)n * DIM;                // maxw*128
  float* pfc   = ph + (size_t)maxw * DIM;                // maxw*128
  int*   deg   = (int*)(pfc + (size_t)maxw * DIM);       // n
  int*   ofs   = deg + n;                                // LVL+1

  hipMemsetAsync(deg, 0, (size_t)n * sizeof(int), stream);
  k_prep<<<512, 256, 0, stream>>>(Wioux, Wiouh, Wfx, Wfh, WcT, WhTp, WfhTp);
  k_levels<<<1, 32, 0, stream>>>(depth, n, ofs, deg);
  k_mark<<<(n + 255) / 256, 256, 0, stream>>>(parent, depth, n, deg);
  k_zero<<<(n + 3) / 4, 256, 0, stream>>>(deg, n, hsum, fcsum);
  k_big<<<(n + 63) / 64, 256, 0, stream>>>(x, WcT, deg, xi, n);

  int kwblocks = ((n + 15) / 16 + 3) / 4;
  for (int d = LVL - 1; d >= 1; --d)
    k_wave<<<kwblocks, 256, 0, stream>>>(x, WhTp, WfhTp, xi, deg, parent, ofs,
                                         h, hsum, fcsum, ph, pfc, n, d);
  k_root<<<1, 256, 0, stream>>>(x, WhTp, xi, deg, ofs, ph, pfc, h);
}